// Round 5
// baseline (187.505 us; speedup 1.0000x reference)
//
#include <hip/hip_runtime.h>

#define N_PTS 128
#define EPS_F 1e-10f
#define FAR_F 1e10f

typedef float f4 __attribute__((ext_vector_type(4)));

// DPP ctrl encodings (gfx9/CDNA):
//   ROW_SHR1=0x111 SHR2=0x112 SHR4=0x114 SHR8=0x118
//   ROW_BCAST15=0x142 ROW_BCAST31=0x143
//   WAVE_SHL1=0x130 (lane i <- i+1)   WAVE_SHR1=0x138 (lane i <- i-1)
template<int CTRL, int ROW_MASK>
__device__ __forceinline__ float dpp_mov(float src, float old) {
    union { float f; int i; } s, o, r;
    s.f = src; o.f = old;
    r.i = __builtin_amdgcn_update_dpp(o.i, s.i, CTRL, ROW_MASK, 0xF, false);
    return r.f;
}

// 32-lane (half-wave) sum; totals land in lane 31 (half A) and lane 63 (half B).
__device__ __forceinline__ float half32_reduce_add(float x) {
    x += dpp_mov<0x111, 0xF>(x, 0.0f);
    x += dpp_mov<0x112, 0xF>(x, 0.0f);
    x += dpp_mov<0x114, 0xF>(x, 0.0f);
    x += dpp_mov<0x118, 0xF>(x, 0.0f);
    x += dpp_mov<0x142, 0xA>(x, 0.0f);  // row1 += lane15 tot, row3 += lane47 tot
    return x;
}

struct Pair { f4 d, z, fa, fb, fc; };   // one ray-pair's inputs (5 x dwordx4)

__device__ __forceinline__ void load_pair(
        Pair& P, const float* __restrict__ density,
        const float* __restrict__ feature, const float* __restrict__ depth,
        int ray, int sub) {
    const size_t doff = (size_t)ray * N_PTS + (sub << 2);
    P.d  = __builtin_nontemporal_load((const f4*)(density + doff));
    P.z  = __builtin_nontemporal_load((const f4*)(depth   + doff));
    const f4* fp = (const f4*)(feature + (size_t)ray * (N_PTS * 3) + sub * 12);
    P.fa = __builtin_nontemporal_load(fp + 0);  // p0x p0y p0z p1x
    P.fb = __builtin_nontemporal_load(fp + 1);  // p1y p1z p2x p2y
    P.fc = __builtin_nontemporal_load(fp + 2);  // p2z p3x p3y p3z
}

// lanes 0-31 = ray A, lanes 32-63 = ray B; lane owns points 4*sub .. 4*sub+3.
__device__ __forceinline__ void process_pair(
        const Pair& P, int sub, int ray, int n_rays, float* __restrict__ out) {
    // deltas: next lane's z0 via wave_shl1; lanes 31/63 overridden with FAR
    float nz = dpp_mov<0x130, 0xF>(P.z.x, 0.0f);
    float d0 = P.z.y - P.z.x;
    float d1 = P.z.z - P.z.y;
    float d2 = P.z.w - P.z.z;
    float d3 = (sub == 31) ? FAR_F : (nz - P.z.w);

    float e0 = __expf(-d0 * P.d.x);
    float e1 = __expf(-d1 * P.d.y);
    float e2 = __expf(-d2 * P.d.z);
    float e3 = __expf(-d3 * P.d.w);
    float a0 = 1.0f - e0, a1 = 1.0f - e1, a2 = 1.0f - e2, a3 = 1.0f - e3;
    float f0 = e0 + EPS_F, f1 = e1 + EPS_F, f2 = e2 + EPS_F, f3 = e3 + EPS_F;

    // local prefix products, then 32-lane inclusive product scan
    float f01  = f0 * f1;
    float f012 = f01 * f2;
    float p    = f012 * f3;
    p *= dpp_mov<0x111, 0xF>(p, 1.0f);
    p *= dpp_mov<0x112, 0xF>(p, 1.0f);
    p *= dpp_mov<0x114, 0xF>(p, 1.0f);
    p *= dpp_mov<0x118, 0xF>(p, 1.0f);
    p *= dpp_mov<0x142, 0xA>(p, 1.0f);       // rows 1,3 *= preceding row total
    float Ts = dpp_mov<0x138, 0xF>(p, 1.0f); // exclusive shift (wave_shr1)
    if (sub == 0) Ts = 1.0f;                 // lane 32 received lane31's value

    float w0 = Ts * a0;
    float T1 = Ts * f0;   float w1 = T1 * a1;
    float T2 = Ts * f01;  float w2 = T2 * a2;
    float T3 = Ts * f012; float w3 = T3 * a3;

    float rx = half32_reduce_add(w0 * P.fa.x + w1 * P.fa.w + w2 * P.fb.z + w3 * P.fc.y);
    float ry = half32_reduce_add(w0 * P.fa.y + w1 * P.fb.x + w2 * P.fb.w + w3 * P.fc.z);
    float rz = half32_reduce_add(w0 * P.fa.z + w1 * P.fb.y + w2 * P.fc.x + w3 * P.fc.w);
    float dd = half32_reduce_add(w0 * P.z.x  + w1 * P.z.y  + w2 * P.z.z  + w3 * P.z.w);

    if (sub == 31) {   // lanes 31 (ray A) and 63 (ray B) hold the totals
        float* o  = out + (size_t)ray * 3;
        __builtin_nontemporal_store(rx, o + 0);
        __builtin_nontemporal_store(ry, o + 1);
        __builtin_nontemporal_store(rz, o + 2);
        float* od = out + (size_t)n_rays * 3 + (size_t)ray * 3;
        __builtin_nontemporal_store(dd, od + 0);
        __builtin_nontemporal_store(dd, od + 1);
        __builtin_nontemporal_store(dd, od + 2);
    }
}

// One-shot waves, 8 rays (4 pairs) per wave. All 20 NT dwordx4 loads issued
// back-to-back (sched_barrier fences them from sinking), then consumed
// pair-by-pair with naturally counted vmcnt waits. Probes whether per-wave
// issue depth (97 KB -> 320 KB in flight per CU) is the remaining limiter.
// __launch_bounds__(256,2): 256-VGPR budget so the allocator has no
// occupancy incentive to sink the later stages (R3 failure mode, VGPR=32).
__global__ __launch_bounds__(256, 2) void volrend_kernel(
        const float* __restrict__ density,
        const float* __restrict__ feature,
        const float* __restrict__ depth,
        float* __restrict__ out, int n_rays) {
    const int lane = threadIdx.x & 63;
    const int sub  = lane & 31;
    const int h    = lane >> 5;
    const int gw   = blockIdx.x * 4 + (threadIdx.x >> 6);   // global wave id
    const int base = gw * 8;                                // first of 8 rays

    if (base + 8 <= n_rays) {
        Pair P0, P1, P2, P3;
        load_pair(P0, density, feature, depth, base + 0 + h, sub);
        load_pair(P1, density, feature, depth, base + 2 + h, sub);
        load_pair(P2, density, feature, depth, base + 4 + h, sub);
        load_pair(P3, density, feature, depth, base + 6 + h, sub);
        __builtin_amdgcn_sched_barrier(0);   // keep all 20 loads issued here
        process_pair(P0, sub, base + 0 + h, n_rays, out);   // vmcnt(15)
        process_pair(P1, sub, base + 2 + h, n_rays, out);   // vmcnt(10)
        process_pair(P2, sub, base + 4 + h, n_rays, out);   // vmcnt(5)
        process_pair(P3, sub, base + 6 + h, n_rays, out);   // vmcnt(0)
    } else {
        for (int pi = 0; pi < 4; ++pi) {
            const int ray = base + 2 * pi + h;
            if (ray < n_rays) {
                Pair P;
                load_pair(P, density, feature, depth, ray, sub);
                process_pair(P, sub, ray, n_rays, out);
            }
        }
    }
}

extern "C" void kernel_launch(void* const* d_in, const int* in_sizes, int n_in,
                              void* d_out, int out_size, void* d_ws, size_t ws_size,
                              hipStream_t stream) {
    const float* density = (const float*)d_in[0];
    const float* feature = (const float*)d_in[1];
    const float* depth   = (const float*)d_in[2];
    float* out = (float*)d_out;
    const int n_rays = in_sizes[0] / N_PTS;     // 65536
    const int blocks = (n_rays + 31) / 32;      // 32 rays per 256-thread block
    volrend_kernel<<<blocks, 256, 0, stream>>>(density, feature, depth, out, n_rays);
}

// Round 6
// 181.068 us; speedup vs baseline: 1.0356x; 1.0356x over previous
//
#include <hip/hip_runtime.h>

#define N_PTS 128
#define EPS_F 1e-10f
#define FAR_F 1e10f

typedef float f4 __attribute__((ext_vector_type(4)));

// DPP ctrl encodings (gfx9/CDNA):
//   ROW_SHR1=0x111 SHR2=0x112 SHR4=0x114 SHR8=0x118
//   ROW_BCAST15=0x142 ROW_BCAST31=0x143
//   WAVE_SHL1=0x130 (lane i <- i+1)   WAVE_SHR1=0x138 (lane i <- i-1)
template<int CTRL, int ROW_MASK>
__device__ __forceinline__ float dpp_mov(float src, float old) {
    union { float f; int i; } s, o, r;
    s.f = src; o.f = old;
    r.i = __builtin_amdgcn_update_dpp(o.i, s.i, CTRL, ROW_MASK, 0xF, false);
    return r.f;
}

// 32-lane (half-wave) sum; totals land in lane 31 (half A) and lane 63 (half B).
__device__ __forceinline__ float half32_reduce_add(float x) {
    x += dpp_mov<0x111, 0xF>(x, 0.0f);
    x += dpp_mov<0x112, 0xF>(x, 0.0f);
    x += dpp_mov<0x114, 0xF>(x, 0.0f);
    x += dpp_mov<0x118, 0xF>(x, 0.0f);
    x += dpp_mov<0x142, 0xA>(x, 0.0f);  // row1 += lane15 tot, row3 += lane47 tot
    return x;
}

// One wave = 2 rays (lanes 0-31 ray A, lanes 32-63 ray B); lane owns points
// 4*sub .. 4*sub+3. One-shot waves (equal-best structure across R0-R5).
// All input loads NON-TEMPORAL (the one measured win, R4: -18%): read-once
// streams skip L1/L2 allocation, freeing line-fill resources.
__global__ __launch_bounds__(256) void volrend_kernel(
        const float* __restrict__ density,
        const float* __restrict__ feature,
        const float* __restrict__ depth,
        float* __restrict__ out, int n_rays) {
    const int lane = threadIdx.x & 63;
    const int sub  = lane & 31;          // lane within the 32-lane half
    const int h    = lane >> 5;          // which ray of the pair
    const int ray  = blockIdx.x * 8 + (threadIdx.x >> 6) * 2 + h;
    if (ray >= n_rays) return;

    const size_t doff = (size_t)ray * N_PTS + (sub << 2);
    const f4 dns = __builtin_nontemporal_load((const f4*)(density + doff));
    const f4 zz  = __builtin_nontemporal_load((const f4*)(depth   + doff));
    const f4* fp = (const f4*)(feature + (size_t)ray * (N_PTS * 3) + sub * 12);
    const f4 fa = __builtin_nontemporal_load(fp + 0);  // p0x p0y p0z p1x
    const f4 fb = __builtin_nontemporal_load(fp + 1);  // p1y p1z p2x p2y
    const f4 fc = __builtin_nontemporal_load(fp + 2);  // p2z p3x p3y p3z

    // deltas: next lane's z0 via wave_shl1; lanes 31/63 overridden with FAR
    float nz = dpp_mov<0x130, 0xF>(zz.x, 0.0f);
    float d0 = zz.y - zz.x;
    float d1 = zz.z - zz.y;
    float d2 = zz.w - zz.z;
    float d3 = (sub == 31) ? FAR_F : (nz - zz.w);

    float e0 = __expf(-d0 * dns.x);
    float e1 = __expf(-d1 * dns.y);
    float e2 = __expf(-d2 * dns.z);
    float e3 = __expf(-d3 * dns.w);
    float a0 = 1.0f - e0, a1 = 1.0f - e1, a2 = 1.0f - e2, a3 = 1.0f - e3;
    float f0 = e0 + EPS_F, f1 = e1 + EPS_F, f2 = e2 + EPS_F, f3 = e3 + EPS_F;

    // local prefix products, then 32-lane inclusive product scan
    float f01  = f0 * f1;
    float f012 = f01 * f2;
    float p    = f012 * f3;
    p *= dpp_mov<0x111, 0xF>(p, 1.0f);
    p *= dpp_mov<0x112, 0xF>(p, 1.0f);
    p *= dpp_mov<0x114, 0xF>(p, 1.0f);
    p *= dpp_mov<0x118, 0xF>(p, 1.0f);
    p *= dpp_mov<0x142, 0xA>(p, 1.0f);       // rows 1,3 *= preceding row total
    float Ts = dpp_mov<0x138, 0xF>(p, 1.0f); // exclusive shift (wave_shr1)
    if (sub == 0) Ts = 1.0f;                 // lane 32 received lane31's value

    float w0 = Ts * a0;
    float T1 = Ts * f0;   float w1 = T1 * a1;
    float T2 = Ts * f01;  float w2 = T2 * a2;
    float T3 = Ts * f012; float w3 = T3 * a3;

    float rx = half32_reduce_add(w0 * fa.x + w1 * fa.w + w2 * fb.z + w3 * fc.y);
    float ry = half32_reduce_add(w0 * fa.y + w1 * fb.x + w2 * fb.w + w3 * fc.z);
    float rz = half32_reduce_add(w0 * fa.z + w1 * fb.y + w2 * fc.x + w3 * fc.w);
    float dd = half32_reduce_add(w0 * zz.x + w1 * zz.y + w2 * zz.z + w3 * zz.w);

    if (sub == 31) {   // lanes 31 (ray A) and 63 (ray B) hold the totals
        float* o  = out + (size_t)ray * 3;
        o[0] = rx; o[1] = ry; o[2] = rz;
        float* od = out + (size_t)n_rays * 3 + (size_t)ray * 3;
        od[0] = dd; od[1] = dd; od[2] = dd;
    }
}

extern "C" void kernel_launch(void* const* d_in, const int* in_sizes, int n_in,
                              void* d_out, int out_size, void* d_ws, size_t ws_size,
                              hipStream_t stream) {
    const float* density = (const float*)d_in[0];
    const float* feature = (const float*)d_in[1];
    const float* depth   = (const float*)d_in[2];
    float* out = (float*)d_out;
    const int n_rays = in_sizes[0] / N_PTS;   // 65536
    const int blocks = (n_rays + 7) / 8;      // 8 rays per 256-thread block
    volrend_kernel<<<blocks, 256, 0, stream>>>(density, feature, depth, out, n_rays);
}